// Round 7
// baseline (1616.365 us; speedup 1.0000x reference)
//
#include <hip/hip_runtime.h>

namespace {

constexpr int kB  = 16;
constexpr int kNC = 31;
constexpr int kNX = 256;   // rows (H)
constexpr int kNY = 256;   // cols (W)
constexpr int kNO = 3;
constexpr int kKS = 17;
constexpr int NOC = kNO * kNC;   // 93

constexpr int TX  = 64;          // output cols per block
constexpr int TY  = 64;          // output rows per block
constexpr int HTY = TY + 8;      // 72 staged rows (halo +-4)
constexpr int NF4 = 19;          // float4 chunks per staged row (76 cols)
constexpr int XP  = 80;          // pitch: mult of 4 -> all b128 aligned; even banks
constexpr int W12 = 12;          // expanded taps (9 + residual shift 0..3)
constexpr int NSTG = HTY * NF4;  // 1368 staging chunks per tile

// ---------------------------------------------------------------------------
// prep: expand each 9-tap weight row to 12 taps with the residual shift rs
// pre-applied (w12[d'] = relu(w[d'-rs]) for d' in [rs,rs+9), else 0), and
// write soaTab[oc] = so & ~3 (aligned part of the shift, used in staging).
// ---------------------------------------------------------------------------
__global__ void prep(const float* __restrict__ vk, const int* __restrict__ loc,
                     float* __restrict__ w12, int* __restrict__ soaTab)
{
    int i = blockIdx.x * 256 + threadIdx.x;
    if (i < NOC * 9 * W12) {
        int row = i / W12;             // row = oc*9 + dy
        int dp  = i - row * W12;       // d' in [0,12)
        int oc  = row / 9;
        int so  = loc[oc * 81] - (oc * kKS + 4) * kKS;   // so = cx-4, in [0,8]
        int rs  = so & 3;
        float v = 0.0f;
        if (dp >= rs && dp < rs + 9) {
            float t = vk[row * 9 + (dp - rs)];
            v = t > 0.0f ? t : 0.0f;
        }
        w12[i] = v;
    }
    if (i < NOC) {
        int so = loc[i * 81] - (i * kKS + 4) * kKS;
        soaTab[i] = so & ~3;           // in {0,4,8}
    }
}

// One (batch, order, 64x64 tile) per block; 16x16 threads, 4x4 outputs each.
// Double-buffered channel loop: prefetch c+1's tile into registers, compute c,
// write prefetch to the other LDS buffer, ONE barrier per channel.
__global__ __launch_bounds__(256, 3)
void disperse_conv(const float* __restrict__ x,
                   const float* __restrict__ w12,
                   const int* __restrict__ soaTab,
                   float* __restrict__ out)
{
    __shared__ __align__(16) float xt[2][HTY * XP];   // 2 x 23,040 B

    const int tid = threadIdx.x;
    const int x0 = blockIdx.x * TX;
    const int y0 = blockIdx.y * TY;
    const int bz = blockIdx.z;         // 48, order-adjacent: bz = b*3 + o
    const int b  = bz / 3;
    const int o  = bz - 3 * b;

    const int tx = tid & 15;           // 16 threads across x
    const int ty = tid >> 4;           // 16 threads down y
    const int xo = tx * 4;

    // this thread's 6 staging slots (slot 5 partially valid: tid < 88)
    int sr[6], sm[6];
    #pragma unroll
    for (int it = 0; it < 6; ++it) {
        int i = it * 256 + tid;
        sr[it] = i / NF4;
        sm[it] = i - NF4 * sr[it];
    }

    // --- prologue: stage channel 0 directly into buffer 0 ---
    {
        const int soa = soaTab[o * kNC];
        const float* xc = x + (size_t)(b * kNC) * kNX * kNY;
        #pragma unroll
        for (int it = 0; it < 6; ++it) {
            int i = it * 256 + tid;
            if (i < NSTG) {
                int gy  = y0 - 4 + sr[it];
                int gxa = x0 + soa - 8 + sm[it] * 4;
                float4 v = make_float4(0.f, 0.f, 0.f, 0.f);
                if ((unsigned)gy < (unsigned)kNX && (unsigned)gxa < (unsigned)kNY)
                    v = *(const float4*)(xc + (size_t)gy * kNY + gxa);
                *(float4*)&xt[0][sr[it] * XP + sm[it] * 4] = v;
            }
        }
    }
    __syncthreads();

    float acc[4][4];
    #pragma unroll
    for (int jr = 0; jr < 4; ++jr)
        #pragma unroll
        for (int jj = 0; jj < 4; ++jj)
            acc[jr][jj] = 0.0f;

    for (int c = 0; c < kNC; ++c) {
        // --- issue prefetch loads for channel c+1 (in flight during compute) ---
        float4 p0 = make_float4(0.f, 0.f, 0.f, 0.f);
        float4 p1 = p0, p2 = p0, p3 = p0, p4 = p0, p5 = p0;
        const bool pfv = (c + 1 < kNC);
        if (pfv) {
            const int soa1 = soaTab[o * kNC + c + 1];
            const float* xc1 = x + (size_t)(b * kNC + c + 1) * kNX * kNY;
            int gy, gxa;
            gy = y0 - 4 + sr[0]; gxa = x0 + soa1 - 8 + sm[0] * 4;
            if ((unsigned)gy < 256u && (unsigned)gxa < 256u) p0 = *(const float4*)(xc1 + (size_t)gy * kNY + gxa);
            gy = y0 - 4 + sr[1]; gxa = x0 + soa1 - 8 + sm[1] * 4;
            if ((unsigned)gy < 256u && (unsigned)gxa < 256u) p1 = *(const float4*)(xc1 + (size_t)gy * kNY + gxa);
            gy = y0 - 4 + sr[2]; gxa = x0 + soa1 - 8 + sm[2] * 4;
            if ((unsigned)gy < 256u && (unsigned)gxa < 256u) p2 = *(const float4*)(xc1 + (size_t)gy * kNY + gxa);
            gy = y0 - 4 + sr[3]; gxa = x0 + soa1 - 8 + sm[3] * 4;
            if ((unsigned)gy < 256u && (unsigned)gxa < 256u) p3 = *(const float4*)(xc1 + (size_t)gy * kNY + gxa);
            gy = y0 - 4 + sr[4]; gxa = x0 + soa1 - 8 + sm[4] * 4;
            if ((unsigned)gy < 256u && (unsigned)gxa < 256u) p4 = *(const float4*)(xc1 + (size_t)gy * kNY + gxa);
            if (tid < NSTG - 1280) {   // slot 5 valid for tid < 88
                gy = y0 - 4 + sr[5]; gxa = x0 + soa1 - 8 + sm[5] * 4;
                if ((unsigned)gy < 256u && (unsigned)gxa < 256u) p5 = *(const float4*)(xc1 + (size_t)gy * kNY + gxa);
            }
        }

        // --- compute channel c from buffer c&1 (R6-proven body) ---
        const float* buf = &xt[c & 1][0];
        const float* wch = w12 + (size_t)((o * kNC + c) * 9) * W12;
        #pragma unroll
        for (int m = 0; m < 12; ++m) {
            const float* pp = &buf[(ty * 4 + m) * XP + xo];   // 16B aligned
            const float4 q0 = *(const float4*)(pp);
            const float4 q1 = *(const float4*)(pp + 4);
            const float4 q2 = *(const float4*)(pp + 8);
            const float4 q3 = *(const float4*)(pp + 12);
            const float xr[16] = { q0.x, q0.y, q0.z, q0.w,
                                   q1.x, q1.y, q1.z, q1.w,
                                   q2.x, q2.y, q2.z, q2.w,
                                   q3.x, q3.y, q3.z, q3.w };

            #pragma unroll
            for (int jr = 0; jr < 4; ++jr) {
                const int dy = m - jr;
                if (dy < 0 || dy >= 9) continue;       // folds at compile time
                const float* wr = wch + dy * W12;      // block-uniform -> s_load
                const float4 wa = *(const float4*)(wr);
                const float4 wb = *(const float4*)(wr + 4);
                const float4 wc = *(const float4*)(wr + 8);

                #pragma unroll
                for (int jj = 0; jj < 4; ++jj) {
                    float a = acc[jr][jj];
                    a = fmaf(wa.x, xr[jj + 0], a);
                    a = fmaf(wa.y, xr[jj + 1], a);
                    a = fmaf(wa.z, xr[jj + 2], a);
                    a = fmaf(wa.w, xr[jj + 3], a);
                    a = fmaf(wb.x, xr[jj + 4], a);
                    a = fmaf(wb.y, xr[jj + 5], a);
                    a = fmaf(wb.z, xr[jj + 6], a);
                    a = fmaf(wb.w, xr[jj + 7], a);
                    a = fmaf(wc.x, xr[jj + 8], a);
                    a = fmaf(wc.y, xr[jj + 9], a);
                    a = fmaf(wc.z, xr[jj + 10], a);
                    a = fmaf(wc.w, xr[jj + 11], a);
                    acc[jr][jj] = a;
                }
            }
        }

        // --- drain prefetch into the other buffer, one barrier per channel ---
        if (pfv) {
            float* dst = &xt[(c + 1) & 1][0];
            *(float4*)&dst[sr[0] * XP + sm[0] * 4] = p0;
            *(float4*)&dst[sr[1] * XP + sm[1] * 4] = p1;
            *(float4*)&dst[sr[2] * XP + sm[2] * 4] = p2;
            *(float4*)&dst[sr[3] * XP + sm[3] * 4] = p3;
            *(float4*)&dst[sr[4] * XP + sm[4] * 4] = p4;
            if (tid < NSTG - 1280)
                *(float4*)&dst[sr[5] * XP + sm[5] * 4] = p5;
        }
        __syncthreads();
    }

    // --- epilogue: 4 rows x 4 cols per thread, aligned float4 stores ---
    #pragma unroll
    for (int jr = 0; jr < 4; ++jr) {
        size_t base = (((size_t)b * kNO + o) * kNX + (size_t)(y0 + ty * 4 + jr)) * kNY
                      + (size_t)(x0 + xo);
        *(float4*)(out + base) = make_float4(acc[jr][0], acc[jr][1],
                                             acc[jr][2], acc[jr][3]);
    }
}

} // namespace

extern "C" void kernel_launch(void* const* d_in, const int* in_sizes, int n_in,
                              void* d_out, int out_size, void* d_ws, size_t ws_size,
                              hipStream_t stream)
{
    const float* x  = (const float*)d_in[0];
    const float* vk = (const float*)d_in[1];
    const int* loc  = (const int*)d_in[2];
    float* outp = (float*)d_out;

    float* w12 = (float*)d_ws;                        // 93*9*12 floats = 40,176 B
    int*   soaTab = (int*)(w12 + NOC * 9 * W12);      // 93 ints

    dim3 pgrid((NOC * 9 * W12 + 255) / 256);
    hipLaunchKernelGGL(prep, pgrid, dim3(256), 0, stream, vk, loc, w12, soaTab);

    dim3 grid(kNY / TX, kNX / TY, kB * kNO);   // (4, 4, 48) = 768 blocks
    hipLaunchKernelGGL(disperse_conv, grid, dim3(256), 0, stream,
                       x, w12, soaTab, outp);
}

// Round 8
// 468.400 us; speedup vs baseline: 3.4508x; 3.4508x over previous
//
#include <hip/hip_runtime.h>

namespace {

constexpr int kB  = 16;
constexpr int kNC = 31;
constexpr int kNX = 256;   // rows (H)
constexpr int kNY = 256;   // cols (W)
constexpr int kNO = 3;
constexpr int kKS = 17;
constexpr int NOC = kNO * kNC;   // 93

constexpr int TX  = 64;          // output cols per block
constexpr int TY  = 64;          // output rows per block
constexpr int HTY = TY + 8;      // 72 staged rows (halo +-4)
constexpr int NF4 = 19;          // float4 chunks per staged row (76 cols)
constexpr int XP  = 80;          // pitch: mult of 4 -> all b128 aligned; even banks
constexpr int W12 = 12;          // expanded taps (9 + residual shift 0..3)
constexpr int NSPL = 2;          // channel split: [0,16) and [16,31)

// ---------------------------------------------------------------------------
// prep: expand each 9-tap weight row to 12 taps with the residual shift rs
// pre-applied (w12[d'] = relu(w[d'-rs]) for d' in [rs,rs+9), else 0), and
// write soaTab[oc] = so & ~3 (aligned part of the shift, used in staging).
// ---------------------------------------------------------------------------
__global__ void prep(const float* __restrict__ vk, const int* __restrict__ loc,
                     float* __restrict__ w12, int* __restrict__ soaTab)
{
    int i = blockIdx.x * 256 + threadIdx.x;
    if (i < NOC * 9 * W12) {
        int row = i / W12;             // row = oc*9 + dy
        int dp  = i - row * W12;       // d' in [0,12)
        int oc  = row / 9;
        int so  = loc[oc * 81] - (oc * kKS + 4) * kKS;   // so = cx-4, in [0,8]
        int rs  = so & 3;
        float v = 0.0f;
        if (dp >= rs && dp < rs + 9) {
            float t = vk[row * 9 + (dp - rs)];
            v = t > 0.0f ? t : 0.0f;
        }
        w12[i] = v;
    }
    if (i < NOC) {
        int so = loc[i * 81] - (i * kKS + 4) * kKS;
        soaTab[i] = so & ~3;           // in {0,4,8}
    }
}

// One (batch, order, channel-half, 64x64 tile) per block; 16x16 threads,
// 4x4 outputs each. Body is the R6-proven scratch-free pattern VERBATIM
// (register prefetch across the unrolled body causes scratch demotion - R7).
// Channel split doubles the grid to 6 blocks/CU so barrier drains overlap;
// halves combine via fp32 global atomicAdd onto a zeroed output.
__global__ __launch_bounds__(256, 6)
void disperse_conv(const float* __restrict__ x,
                   const float* __restrict__ w12,
                   const int* __restrict__ soaTab,
                   float* __restrict__ out)
{
    __shared__ __align__(16) float xtile[HTY * XP];   // 23,040 B

    const int tid = threadIdx.x;
    const int x0 = blockIdx.x * TX;
    const int y0 = blockIdx.y * TY;
    const int bz = blockIdx.z;         // 96 = b*6 + o*2 + s (same-x blocks adjacent)
    const int b  = bz / 6;
    const int r6 = bz - 6 * b;
    const int o  = r6 >> 1;
    const int s  = r6 & 1;
    const int cbeg = s ? 16 : 0;
    const int cend = s ? kNC : 16;

    const int tx = tid & 15;           // 16 threads across x
    const int ty = tid >> 4;           // 16 threads down y
    const int xo = tx * 4;             // 4 consecutive output cols per thread

    float acc[4][4];
    #pragma unroll
    for (int jr = 0; jr < 4; ++jr)
        #pragma unroll
        for (int jj = 0; jj < 4; ++jj)
            acc[jr][jj] = 0.0f;

    for (int c = cbeg; c < cend; ++c) {
        const int soa = soaTab[o * kNC + c];           // block-uniform {0,4,8}
        const float* wch = w12 + (size_t)((o * kNC + c) * 9) * W12;
        const float* xc  = x + (size_t)(b * kNC + c) * kNX * kNY;

        __syncthreads();   // protect previous tile before overwrite
        // --- stage pre-shifted tile: LDS[r][k'] = x[y0-4+r][x0+soa-8+k'] ---
        #pragma unroll
        for (int it = 0; it < 6; ++it) {               // 1368 f4 over 256 thr
            int i = it * 256 + tid;
            if (i < HTY * NF4) {
                int rr = i / NF4;
                int mc = i - rr * NF4;
                int gy = y0 - 4 + rr;
                int gx = x0 + soa - 8 + mc * 4;        // mult of 4: aligned f4
                float4 v = make_float4(0.f, 0.f, 0.f, 0.f);
                if ((unsigned)gy < (unsigned)kNX && (unsigned)gx < (unsigned)kNY)
                    v = *(const float4*)(xc + (size_t)gy * kNY + gx);
                *(float4*)&xtile[rr * XP + mc * 4] = v;   // aligned b128 write
            }
        }
        __syncthreads();

        // --- compute: input rows m=0..11 feed output rows jr=0..3 (dy=m-jr) ---
        #pragma unroll
        for (int m = 0; m < 12; ++m) {
            const float* pp = &xtile[(ty * 4 + m) * XP + xo];   // 16B aligned
            const float4 q0 = *(const float4*)(pp);
            const float4 q1 = *(const float4*)(pp + 4);
            const float4 q2 = *(const float4*)(pp + 8);
            const float4 q3 = *(const float4*)(pp + 12);
            const float xr[16] = { q0.x, q0.y, q0.z, q0.w,
                                   q1.x, q1.y, q1.z, q1.w,
                                   q2.x, q2.y, q2.z, q2.w,
                                   q3.x, q3.y, q3.z, q3.w };

            #pragma unroll
            for (int jr = 0; jr < 4; ++jr) {
                const int dy = m - jr;
                if (dy < 0 || dy >= 9) continue;       // folds at compile time
                const float* wr = wch + dy * W12;      // block-uniform -> s_load
                const float4 wa = *(const float4*)(wr);
                const float4 wb = *(const float4*)(wr + 4);
                const float4 wc = *(const float4*)(wr + 8);

                #pragma unroll
                for (int jj = 0; jj < 4; ++jj) {
                    float a = acc[jr][jj];
                    a = fmaf(wa.x, xr[jj + 0], a);
                    a = fmaf(wa.y, xr[jj + 1], a);
                    a = fmaf(wa.z, xr[jj + 2], a);
                    a = fmaf(wa.w, xr[jj + 3], a);
                    a = fmaf(wb.x, xr[jj + 4], a);
                    a = fmaf(wb.y, xr[jj + 5], a);
                    a = fmaf(wb.z, xr[jj + 6], a);
                    a = fmaf(wb.w, xr[jj + 7], a);
                    a = fmaf(wc.x, xr[jj + 8], a);
                    a = fmaf(wc.y, xr[jj + 9], a);
                    a = fmaf(wc.z, xr[jj + 10], a);
                    a = fmaf(wc.w, xr[jj + 11], a);
                    acc[jr][jj] = a;
                }
            }
        }
    }

    // --- epilogue: accumulate both channel-halves via device-scope atomics ---
    #pragma unroll
    for (int jr = 0; jr < 4; ++jr) {
        size_t base = (((size_t)b * kNO + o) * kNX + (size_t)(y0 + ty * 4 + jr)) * kNY
                      + (size_t)(x0 + xo);
        #pragma unroll
        for (int jj = 0; jj < 4; ++jj)
            atomicAdd(out + base + jj, acc[jr][jj]);
    }
}

} // namespace

extern "C" void kernel_launch(void* const* d_in, const int* in_sizes, int n_in,
                              void* d_out, int out_size, void* d_ws, size_t ws_size,
                              hipStream_t stream)
{
    const float* x  = (const float*)d_in[0];
    const float* vk = (const float*)d_in[1];
    const int* loc  = (const int*)d_in[2];
    float* outp = (float*)d_out;

    float* w12 = (float*)d_ws;                        // 93*9*12 floats = 40,176 B
    int*   soaTab = (int*)(w12 + NOC * 9 * W12);      // 93 ints

    // output accumulates across the two channel-split halves -> start at zero
    hipMemsetAsync(d_out, 0, (size_t)out_size * sizeof(float), stream);

    dim3 pgrid((NOC * 9 * W12 + 255) / 256);
    hipLaunchKernelGGL(prep, pgrid, dim3(256), 0, stream, vk, loc, w12, soaTab);

    dim3 grid(kNY / TX, kNX / TY, kB * kNO * NSPL);   // (4, 4, 96) = 1536 blocks
    hipLaunchKernelGGL(disperse_conv, grid, dim3(256), 0, stream,
                       x, w12, soaTab, outp);
}